// Round 5
// baseline (1095.809 us; speedup 1.0000x reference)
//
#include <hip/hip_runtime.h>
#include <hip/hip_bf16.h>

// FocalNet block, MI355X gfx950.
// R9: R8 post-mortem showed __launch_bounds__(512,4) is a one-sided hint: the
//     allocator targeted 8 waves/EU -> 64 VGPR -> spills returned (WRITE 270MB,
//     FETCH 402MB). Fix: amdgpu_waves_per_eu(4,4) pins the budget at 128 VGPR
//     (live set ~110, no spill possible); wave grid flipped 2x4 -> 4x2 so the
//     4x-duplicated operand is the L2-resident weight, not the 51MB activation.

#define NT 200704   // B*H*W
#define CC 128
#define HH 56
#define WW 56
#define BB 64

typedef short short8 __attribute__((ext_vector_type(8)));
typedef float f32x4  __attribute__((ext_vector_type(4)));

__device__ __forceinline__ float b2f(unsigned short u) {
    union { float f; unsigned int i; } v; v.i = ((unsigned int)u) << 16; return v.f;
}
__device__ __forceinline__ unsigned short f2b(float f) {
    __hip_bfloat16 h = __float2bfloat16(f);
    union { __hip_bfloat16 h; unsigned short u; } v; v.h = h; return v.u;
}
// tanh-form gelu: 0.5x(1+tanh(0.79788456(x+0.044715x^3))) == x * sigmoid(2y)
__device__ __forceinline__ float gelu(float x) {
    float x2 = x * x;
    float inner = fmaf(0.044715f * x2, x, x);
    float t = exp2f(inner * -2.302118070f);   // e^{-2*0.79788456*inner}
    return x * __builtin_amdgcn_rcpf(1.0f + t);
}
__device__ __forceinline__ void cvt4(uint2 p, float* o) {
    union { float f; unsigned int i; } v;
    v.i = p.x << 16;         o[0] = v.f;
    v.i = p.x & 0xffff0000u; o[1] = v.f;
    v.i = p.y << 16;         o[2] = v.f;
    v.i = p.y & 0xffff0000u; o[3] = v.f;
}
__device__ __forceinline__ void cvt2(unsigned int p, float* o) {
    union { float f; unsigned int i; } v;
    v.i = p << 16;          o[0] = v.f;
    v.i = p & 0xffff0000u;  o[1] = v.f;
}
__device__ __forceinline__ unsigned int pack2(float a, float b) {
    return (unsigned int)f2b(a) | ((unsigned int)f2b(b) << 16);
}
__device__ __forceinline__ uint2 pack4(const float* s) {
    uint2 r;
    r.x = (unsigned int)f2b(s[0]) | ((unsigned int)f2b(s[1]) << 16);
    r.y = (unsigned int)f2b(s[2]) | ((unsigned int)f2b(s[3]) << 16);
    return r;
}
__device__ __forceinline__ short8 ldfrag_g(const unsigned short* p) {
    union { uint4 u; short8 s; } v;
    v.u = *(const uint4*)p;
    return v.s;
}
__device__ __forceinline__ short8 ldfrag_s(const unsigned short* p) {
    return *(const short8*)p;
}

// ---------------- weight prep: fp32 (K,M) row-major -> bf16 (M,K) ----------------
__global__ void transpose_bf16_k(const float* __restrict__ src, unsigned short* __restrict__ dst,
                                 int K, int M, int src_ld) {
    int idx = blockIdx.x * 256 + threadIdx.x;
    if (idx >= K * M) return;
    int k = idx / M, m = idx - k * M;
    dst[m * K + k] = f2b(src[k * src_ld + m]);
}
// fc2_w (512,128) -> (4 chunks, 128 out, 128 k-local)
__global__ void transpose_fc2c_k(const float* __restrict__ src, unsigned short* __restrict__ dst) {
    int idx = blockIdx.x * 256 + threadIdx.x;
    if (idx >= 512 * 128) return;
    int k = idx >> 7, m = idx & 127;
    int hc = k >> 7, kl = k & 127;
    dst[hc * 16384 + m * 128 + kl] = f2b(src[k * 128 + m]);
}

// ---------------- LN1 + gate dots (wave per token) ----------------
__global__ __launch_bounds__(256) void ln1_gates_k(
    const float* __restrict__ x, const float* __restrict__ g, const float* __restrict__ bta,
    const float* __restrict__ fw, const float* __restrict__ fb,
    unsigned short* __restrict__ ybf, float* __restrict__ gates)
{
    int lane = threadIdx.x & 63, wv = threadIdx.x >> 6;
    int token = blockIdx.x * 4 + wv;
    float2 xv = *(const float2*)&x[(size_t)token * CC + lane * 2];
    float s = xv.x + xv.y;
    for (int o = 32; o; o >>= 1) s += __shfl_xor(s, o);
    float mu = s * (1.0f / 128.0f);
    float d0 = xv.x - mu, d1 = xv.y - mu;
    float q2 = d0 * d0 + d1 * d1;
    for (int o = 32; o; o >>= 1) q2 += __shfl_xor(q2, o);
    float rs = rsqrtf(q2 * (1.0f / 128.0f) + 1e-5f);
    float y0 = d0 * rs * g[2 * lane] + bta[2 * lane];
    float y1 = d1 * rs * g[2 * lane + 1] + bta[2 * lane + 1];
    unsigned int pk = (unsigned int)f2b(y0) | ((unsigned int)f2b(y1) << 16);
    ((unsigned int*)ybf)[(size_t)token * 64 + lane] = pk;
    float ga[4];
    #pragma unroll
    for (int gg = 0; gg < 4; gg++)
        ga[gg] = y0 * fw[(2 * lane) * 260 + 256 + gg] + y1 * fw[(2 * lane + 1) * 260 + 256 + gg];
    for (int o = 32; o; o >>= 1) {
        #pragma unroll
        for (int gg = 0; gg < 4; gg++) ga[gg] += __shfl_xor(ga[gg], o);
    }
    if (lane == 0) {
        float4 gv = make_float4(ga[0] + fb[256], ga[1] + fb[257], ga[2] + fb[258], ga[3] + fb[259]);
        *(float4*)&gates[(size_t)token * 4] = gv;
    }
}

// ---------------- LN2 (wave per token) ----------------
__global__ __launch_bounds__(256) void ln2_k(
    const float* __restrict__ x, const float* __restrict__ g, const float* __restrict__ bta,
    unsigned short* __restrict__ ybf)
{
    int lane = threadIdx.x & 63, wv = threadIdx.x >> 6;
    int token = blockIdx.x * 4 + wv;
    float2 xv = *(const float2*)&x[(size_t)token * CC + lane * 2];
    float s = xv.x + xv.y;
    for (int o = 32; o; o >>= 1) s += __shfl_xor(s, o);
    float mu = s * (1.0f / 128.0f);
    float d0 = xv.x - mu, d1 = xv.y - mu;
    float q2 = d0 * d0 + d1 * d1;
    for (int o = 32; o; o >>= 1) q2 += __shfl_xor(q2, o);
    float rs = rsqrtf(q2 * (1.0f / 128.0f) + 1e-5f);
    float y0 = d0 * rs * g[2 * lane] + bta[2 * lane];
    float y1 = d1 * rs * g[2 * lane + 1] + bta[2 * lane + 1];
    unsigned int pk = (unsigned int)f2b(y0) | ((unsigned int)f2b(y1) << 16);
    ((unsigned int*)ybf)[(size_t)token * 64 + lane] = pk;
}

// ================= GEMM building block macros =================
// 128x128 tile, 8 waves 4x2 (4 row-groups x 2 col-groups), wave does 32x64
// via 2x4 mfma_16x16x32_bf16. B (weights, L2-hot) is duplicated 4x; A
// (streamed activations) only 2x. amdgpu_waves_per_eu(4,4) pins the VGPR
// budget at 128 so the ~110-reg live set never spills.

#define GEMM_ATTR __attribute__((amdgpu_waves_per_eu(4, 4)))

#define GEMM_IDS \
    const int row0 = blockIdx.x * 128; \
    const int lane = threadIdx.x & 63, wv = threadIdx.x >> 6; \
    const int wy = wv >> 1, wx = wv & 1; \
    const int q4 = lane >> 4, l16 = lane & 15; (void)row0;

#define ZERO_ACC(acc) \
    _Pragma("unroll") for (int i = 0; i < 2; i++) \
    _Pragma("unroll") for (int j = 0; j < 4; j++) acc[i][j] = (f32x4)0.0f;

#define MFMA_ALL(acc, af, bf) \
    _Pragma("unroll") for (int i = 0; i < 2; i++) \
    _Pragma("unroll") for (int j = 0; j < 4; j++) \
        acc[i][j] = __builtin_amdgcn_mfma_f32_16x16x32_bf16(af[i], bf[j], acc[i][j], 0, 0, 0);

// ---------------- fused q+ctx GEMM: t = y @ f_w[:, :256] ----------------
// q written token-major; ctx written SLAB-MAJOR [(s*NT + tok)*4 + e] via LDS stage.
__global__ __launch_bounds__(512) GEMM_ATTR void gemm_f2_k(
    const unsigned short* __restrict__ A, const unsigned short* __restrict__ Wt,
    const float* __restrict__ fb,
    unsigned short* __restrict__ outq, unsigned short* __restrict__ outcT)
{
    __shared__ unsigned short Gs[32 * 268];   // [slab][tok*4+e], stride 268 (8B-aligned rows, ~2-way banks)
    GEMM_IDS;
    for (int mo = 0; mo < 2; mo++) {
        f32x4 acc[2][4];
        ZERO_ACC(acc);
        for (int kk = 0; kk < 128; kk += 32) {
            short8 af[2], bf[4];
            #pragma unroll
            for (int i = 0; i < 2; i++)
                af[i] = ldfrag_g(&A[(size_t)(row0 + wy * 32 + i * 16 + l16) * 128 + kk + q4 * 8]);
            #pragma unroll
            for (int j = 0; j < 4; j++)
                bf[j] = ldfrag_g(&Wt[(size_t)(mo * 128 + wx * 64 + j * 16 + l16) * 128 + kk + q4 * 8]);
            MFMA_ALL(acc, af, bf);
        }
        if (mo == 0) {
            #pragma unroll
            for (int i = 0; i < 2; i++)
                #pragma unroll
                for (int j = 0; j < 4; j++)
                    #pragma unroll
                    for (int rr = 0; rr < 4; rr++) {
                        int row = row0 + wy * 32 + i * 16 + q4 * 4 + rr;
                        int col = wx * 64 + j * 16 + l16;
                        outq[(size_t)row * CC + col] = f2b(acc[i][j][rr] + fb[col]);
                    }
        } else {
            #pragma unroll
            for (int i = 0; i < 2; i++)
                #pragma unroll
                for (int j = 0; j < 4; j++)
                    #pragma unroll
                    for (int rr = 0; rr < 4; rr++) {
                        int row_l = wy * 32 + i * 16 + q4 * 4 + rr;
                        int col = wx * 64 + j * 16 + l16;
                        Gs[(col >> 2) * 268 + row_l * 4 + (col & 3)] = f2b(acc[i][j][rr] + fb[128 + col]);
                    }
            __syncthreads();
            // 32 slabs x 128 tokens of uint2 -> contiguous 1KB runs per slab
            #pragma unroll
            for (int it = 0; it < 8; it++) {
                int c = it * 512 + threadIdx.x;
                int s = c >> 7, tok = c & 127;
                *(uint2*)&outcT[((size_t)s * NT + row0 + tok) * 4] =
                    *(const uint2*)&Gs[s * 268 + tok * 4];
            }
        }
    }
}

// ---------------- fused h + proj GEMM ----------------
// x_out = q * (ctx_all @ h_w + h_b);  x1 = x + x_out @ proj_w + proj_b -> d_out (fp32)
// CA is SLAB-MAJOR: fragment = two uint2 from adjacent slab planes.
__global__ __launch_bounds__(512) GEMM_ATTR void gemm_hproj_k(
    const unsigned short* __restrict__ CA, const unsigned short* __restrict__ Wh,
    const float* __restrict__ hb, const unsigned short* __restrict__ Qm,
    const unsigned short* __restrict__ Wp, const float* __restrict__ pb,
    const float* __restrict__ xin, float* __restrict__ outp)
{
    __shared__ unsigned short Gs[128 * 136];
    GEMM_IDS;
    f32x4 acc[2][4];
    ZERO_ACC(acc);
    for (int kk = 0; kk < 128; kk += 32) {
        short8 af[2], bf[4];
        int s0 = (kk >> 2) + q4 * 2;
        #pragma unroll
        for (int i = 0; i < 2; i++) {
            int row = row0 + wy * 32 + i * 16 + l16;
            union { uint2 u[2]; short8 s; } v;
            v.u[0] = *(const uint2*)&CA[((size_t)s0 * NT + row) * 4];
            v.u[1] = *(const uint2*)&CA[((size_t)(s0 + 1) * NT + row) * 4];
            af[i] = v.s;
        }
        #pragma unroll
        for (int j = 0; j < 4; j++)
            bf[j] = ldfrag_g(&Wh[(size_t)(wx * 64 + j * 16 + l16) * 128 + kk + q4 * 8]);
        MFMA_ALL(acc, af, bf);
    }
    #pragma unroll
    for (int i = 0; i < 2; i++)
        #pragma unroll
        for (int j = 0; j < 4; j++)
            #pragma unroll
            for (int rr = 0; rr < 4; rr++) {
                int row_l = wy * 32 + i * 16 + q4 * 4 + rr;
                int col_l = wx * 64 + j * 16 + l16;
                float v = acc[i][j][rr] + hb[col_l];
                float qv = b2f(Qm[(size_t)(row0 + row_l) * CC + col_l]);
                Gs[row_l * 136 + col_l] = f2b(v * qv);
            }
    __syncthreads();
    ZERO_ACC(acc);
    for (int kk = 0; kk < 128; kk += 32) {
        short8 af[2], bf[4];
        #pragma unroll
        for (int i = 0; i < 2; i++)
            af[i] = ldfrag_s(&Gs[(wy * 32 + i * 16 + l16) * 136 + kk + q4 * 8]);
        #pragma unroll
        for (int j = 0; j < 4; j++)
            bf[j] = ldfrag_g(&Wp[(size_t)(wx * 64 + j * 16 + l16) * 128 + kk + q4 * 8]);
        MFMA_ALL(acc, af, bf);
    }
    #pragma unroll
    for (int i = 0; i < 2; i++)
        #pragma unroll
        for (int j = 0; j < 4; j++)
            #pragma unroll
            for (int rr = 0; rr < 4; rr++) {
                int row = row0 + wy * 32 + i * 16 + q4 * 4 + rr;
                int col = wx * 64 + j * 16 + l16;
                size_t oi = (size_t)row * CC + col;
                outp[oi] = acc[i][j][rr] + pb[col] + xin[oi];
            }
}

// ---------------- fused MLP: out += gelu(m@fc1+b1)@fc2 + b2 (4 hidden chunks) ----------------
__global__ __launch_bounds__(512) GEMM_ATTR void gemm_mlp_k(
    const unsigned short* __restrict__ M, const unsigned short* __restrict__ W1,
    const float* __restrict__ b1, const unsigned short* __restrict__ W2,
    const float* __restrict__ b2, float* __restrict__ outp)
{
    __shared__ unsigned short Gs[128 * 136];
    GEMM_IDS;
    f32x4 accO[2][4];
    ZERO_ACC(accO);
    for (int hc = 0; hc < 4; hc++) {
        f32x4 accG[2][4];
        ZERO_ACC(accG);
        for (int kk = 0; kk < 128; kk += 32) {
            short8 af[2], bf[4];
            #pragma unroll
            for (int i = 0; i < 2; i++)
                af[i] = ldfrag_g(&M[(size_t)(row0 + wy * 32 + i * 16 + l16) * 128 + kk + q4 * 8]);
            #pragma unroll
            for (int j = 0; j < 4; j++)
                bf[j] = ldfrag_g(&W1[(size_t)(hc * 128 + wx * 64 + j * 16 + l16) * 128 + kk + q4 * 8]);
            MFMA_ALL(accG, af, bf);
        }
        __syncthreads();   // prior chunk's Gs reads complete
        #pragma unroll
        for (int i = 0; i < 2; i++)
            #pragma unroll
            for (int j = 0; j < 4; j++)
                #pragma unroll
                for (int rr = 0; rr < 4; rr++) {
                    int row_l = wy * 32 + i * 16 + q4 * 4 + rr;
                    int col_l = wx * 64 + j * 16 + l16;
                    Gs[row_l * 136 + col_l] = f2b(gelu(accG[i][j][rr] + b1[hc * 128 + col_l]));
                }
        __syncthreads();
        for (int kk = 0; kk < 128; kk += 32) {
            short8 af[2], bf[4];
            #pragma unroll
            for (int i = 0; i < 2; i++)
                af[i] = ldfrag_s(&Gs[(wy * 32 + i * 16 + l16) * 136 + kk + q4 * 8]);
            #pragma unroll
            for (int j = 0; j < 4; j++)
                bf[j] = ldfrag_g(&W2[(size_t)hc * 16384 + (wx * 64 + j * 16 + l16) * 128 + kk + q4 * 8]);
            MFMA_ALL(accO, af, bf);
        }
    }
    #pragma unroll
    for (int i = 0; i < 2; i++)
        #pragma unroll
        for (int j = 0; j < 4; j++)
            #pragma unroll
            for (int rr = 0; rr < 4; rr++) {
                int row = row0 + wy * 32 + i * 16 + q4 * 4 + rr;
                int col = wx * 64 + j * 16 + l16;
                size_t oi = (size_t)row * CC + col;
                outp[oi] = accO[i][j][rr] + b2[col] + outp[oi];
            }
}

// ---------------- fused 3-level depthwise conv chain ----------------
// Block = (4-ch slab, batch image), processed as TWO independent 2-channel
// chains to keep peak live registers ~90 (no spills at the compiler's 128
// budget). uint LDS planes, row stride 65 (bank-conflict pad). Level 3 does
// not write LDS (output dead). Weights for all levels preloaded once.
template<int R, bool SUM>
__device__ __forceinline__ void conv_half(
    const unsigned int* __restrict__ bin, unsigned int* __restrict__ bout,
    const float2* __restrict__ wl2h, int t0, const float* __restrict__ gates,
    int r, int w0, int tok0, int level, float creg[7][2], float psum[2])
{
    constexpr int KS = 2 * R + 1;
    float acc7[7][2];
    #pragma unroll
    for (int i = 0; i < 7; i++) { acc7[i][0] = 0.0f; acc7[i][1] = 0.0f; }
    #pragma unroll
    for (int kh = 0; kh < KS; kh++) {
        const unsigned int* rp = &bin[(r + kh + 3 - R) * 65 + (w0 + 3 - R)];
        float xw[7 + 2 * R][2];
        #pragma unroll
        for (int j = 0; j < 7 + 2 * R; j++) cvt2(rp[j], xw[j]);
        #pragma unroll
        for (int kw = 0; kw < KS; kw++) {
            float2 w2 = wl2h[(t0 + kh * KS + kw) * 2];
            #pragma unroll
            for (int ow = 0; ow < 7; ow++) {
                acc7[ow][0] += xw[ow + kw][0] * w2.x;
                acc7[ow][1] += xw[ow + kw][1] * w2.y;
            }
        }
    }
    #pragma unroll
    for (int ow = 0; ow < 7; ow++) {
        float gt = gates[(size_t)(tok0 + ow) * 4 + level];
        float g0 = gelu(acc7[ow][0]);
        float g1 = gelu(acc7[ow][1]);
        creg[ow][0] += g0 * gt;
        creg[ow][1] += g1 * gt;
        if (SUM) { psum[0] += g0; psum[1] += g1; }
        if (!SUM) bout[(r + 3) * 65 + (w0 + 3 + ow)] = pack2(g0, g1);
    }
}

__global__ __launch_bounds__(448) void dwconv_fused_k(
    const unsigned short* __restrict__ cinT,
    const float* __restrict__ k0w, const float* __restrict__ k1w, const float* __restrict__ k2w,
    const float* __restrict__ gates,
    unsigned short* __restrict__ coutT, float* __restrict__ part)
{
    constexpr int PL = 62 * 65;
    __shared__ unsigned int bufA[2][PL];
    __shared__ unsigned int bufB[2][PL];
    __shared__ float2 wl2[83 * 2];     // [tap: 0..8 k0, 9..33 k1, 34..82 k2][half]
    __shared__ float wred[7][4];
    const int tid = threadIdx.x;
    const int slab = blockIdx.x, b = blockIdx.y;

    for (int i = tid; i < PL; i += 448) {
        bufA[0][i] = 0u; bufA[1][i] = 0u;
        bufB[0][i] = 0u; bufB[1][i] = 0u;
    }
    if (tid < 166) {
        int t = tid >> 1, h = tid & 1;
        const float* src = (t < 9) ? &k0w[t * CC]
                         : (t < 34) ? &k1w[(t - 9) * CC]
                                    : &k2w[(t - 34) * CC];
        wl2[t * 2 + h] = *(const float2*)&src[slab * 4 + h * 2];
    }
    __syncthreads();
    // slab-major: this block's plane is contiguous (3136 x 8B = 25KB)
    const unsigned short* cinS = cinT + ((size_t)slab * BB + b) * 3136 * 4;
    for (int px = tid; px < 3136; px += 448) {
        int rr = px / 56, c = px - rr * 56;
        uint2 v = *(const uint2*)&cinS[(size_t)px * 4];
        bufA[0][(rr + 3) * 65 + c + 3] = v.x;
        bufA[1][(rr + 3) * 65 + c + 3] = v.y;
    }
    __syncthreads();

    const int r = tid >> 3, wt = tid & 7, w0 = wt * 7;
    const int tok0 = b * 3136 + r * 56 + w0;
    float creg[2][7][2];
    #pragma unroll
    for (int h = 0; h < 2; h++)
        #pragma unroll
        for (int i = 0; i < 7; i++) { creg[h][i][0] = 0.0f; creg[h][i][1] = 0.0f; }
    float psum[4] = {0.0f, 0.0f, 0.0f, 0.0f};

    #pragma unroll
    for (int h = 0; h < 2; h++) {
        conv_half<1, false>(bufA[h], bufB[h], wl2 + h, 0,  gates, r, w0, tok0, 0, creg[h], &psum[h * 2]);
        __syncthreads();
        conv_half<2, false>(bufB[h], bufA[h], wl2 + h, 9,  gates, r, w0, tok0, 1, creg[h], &psum[h * 2]);
        __syncthreads();
        conv_half<3, true >(bufA[h], bufB[h], wl2 + h, 34, gates, r, w0, tok0, 2, creg[h], &psum[h * 2]);
    }

    // write ctx_all slab-major (7 consecutive uint2 per thread, coalesced per wave)
    unsigned short* coutS = coutT + ((size_t)slab * BB + b) * 3136 * 4;
    #pragma unroll
    for (int ow = 0; ow < 7; ow++) {
        float s4[4] = {creg[0][ow][0], creg[0][ow][1], creg[1][ow][0], creg[1][ow][1]};
        *(uint2*)&coutS[(size_t)(r * 56 + w0 + ow) * 4] = pack4(s4);
    }

    // block partial sums for the global mean of ctx2
    #pragma unroll
    for (int e = 0; e < 4; e++)
        for (int o = 32; o; o >>= 1) psum[e] += __shfl_xor(psum[e], o);
    if ((tid & 63) == 0) {
        #pragma unroll
        for (int e = 0; e < 4; e++) wred[tid >> 6][e] = psum[e];
    }
    __syncthreads();
    if (tid == 0) {
        float s0 = 0, s1 = 0, s2 = 0, s3 = 0;
        for (int w2 = 0; w2 < 7; w2++) {
            s0 += wred[w2][0]; s1 += wred[w2][1]; s2 += wred[w2][2]; s3 += wred[w2][3];
        }
        float4 res = make_float4(s0, s1, s2, s3);
        *(float4*)&part[((size_t)b * 32 + slab) * 4] = res;
    }
}

// ---------------- cg = gelu(mean) ----------------
__global__ void mean_fin_k(const float* __restrict__ part, float* __restrict__ cg) {
    int b = blockIdx.x, c = threadIdx.x;
    cg[b * CC + c] = gelu(part[b * CC + c] * (1.0f / 3136.0f));
}

// ---------------- acc += cg[b] * gate3 (slab-major acc) ----------------
__global__ __launch_bounds__(256) void addg3_k(
    unsigned short* acc, const float* __restrict__ gates, const float* __restrict__ cg)
{
    unsigned int idx4 = blockIdx.x * 256 + threadIdx.x;   // uint2 chunk over 32*NT
    unsigned int s   = idx4 / NT;
    unsigned int tok = idx4 - s * NT;
    unsigned int b   = tok / 3136;
    float g3 = gates[(size_t)tok * 4 + 3];
    const float* cgp = &cg[b * CC + s * 4];
    uint2 v = *(uint2*)&acc[(size_t)idx4 * 4];
    float f[4];
    cvt4(v, f);
    #pragma unroll
    for (int e = 0; e < 4; e++) f[e] += cgp[e] * g3;
    *(uint2*)&acc[(size_t)idx4 * 4] = pack4(f);
}

extern "C" void kernel_launch(void* const* d_in, const int* in_sizes, int n_in,
                              void* d_out, int out_size, void* d_ws, size_t ws_size,
                              hipStream_t stream) {
    (void)in_sizes; (void)n_in; (void)out_size; (void)ws_size;
    const float* x      = (const float*)d_in[0];
    const float* f_w    = (const float*)d_in[1];
    const float* f_b    = (const float*)d_in[2];
    const float* k0     = (const float*)d_in[3];
    const float* k1     = (const float*)d_in[4];
    const float* k2     = (const float*)d_in[5];
    const float* h_w    = (const float*)d_in[6];
    const float* h_b    = (const float*)d_in[7];
    const float* proj_w = (const float*)d_in[8];
    const float* proj_b = (const float*)d_in[9];
    const float* ln1_g  = (const float*)d_in[10];
    const float* ln1_b  = (const float*)d_in[11];
    const float* ln2_g  = (const float*)d_in[12];
    const float* ln2_b  = (const float*)d_in[13];
    const float* fc1_w  = (const float*)d_in[14];
    const float* fc1_b  = (const float*)d_in[15];
    const float* fc2_w  = (const float*)d_in[16];
    const float* fc2_b  = (const float*)d_in[17];
    float* out = (float*)d_out;

    // ---- workspace bump allocator (256B aligned), total ~103.3 MB ----
    size_t off = 0;
    auto alloc = [&](size_t bytes) -> char* {
        char* p = (char*)d_ws + off;
        off += (bytes + 255) & ~(size_t)255;
        return p;
    };
    unsigned short* wt_f    = (unsigned short*)alloc(256 * 128 * 2);
    unsigned short* wt_h    = (unsigned short*)alloc(128 * 128 * 2);
    unsigned short* wt_proj = (unsigned short*)alloc(128 * 128 * 2);
    unsigned short* wt_fc1  = (unsigned short*)alloc(512 * 128 * 2);
    unsigned short* wt_fc2c = (unsigned short*)alloc(512 * 128 * 2);
    unsigned short* Y       = (unsigned short*)alloc((size_t)NT * CC * 2); // y -> ctx_all(T) -> m
    unsigned short* Q       = (unsigned short*)alloc((size_t)NT * CC * 2); // q
    float*          gates   = (float*)alloc((size_t)NT * 4 * 4);
    float*          part    = (float*)alloc(BB * CC * 4);
    float*          cg      = (float*)alloc(BB * CC * 4);

    // ctx (slab-major) lives in d_out's upper half until the conv consumes it
    unsigned short* p1 = (unsigned short*)d_out + (size_t)NT * CC;

    // ---- 0. weight prep ----
    transpose_bf16_k<<<(128 * 256 + 255) / 256, 256, 0, stream>>>(f_w, wt_f, 128, 256, 260);
    transpose_bf16_k<<<(128 * 128 + 255) / 256, 256, 0, stream>>>(h_w, wt_h, 128, 128, 128);
    transpose_bf16_k<<<(128 * 128 + 255) / 256, 256, 0, stream>>>(proj_w, wt_proj, 128, 128, 128);
    transpose_bf16_k<<<(128 * 512 + 255) / 256, 256, 0, stream>>>(fc1_w, wt_fc1, 128, 512, 512);
    transpose_fc2c_k<<<(512 * 128 + 255) / 256, 256, 0, stream>>>(fc2_w, wt_fc2c);

    // ---- 1. LN1 + gates ----
    ln1_gates_k<<<NT / 4, 256, 0, stream>>>(x, ln1_g, ln1_b, f_w, f_b, Y, gates);

    // ---- 2. q + ctx (ctx slab-major) in one GEMM kernel ----
    gemm_f2_k<<<NT / 128, 512, 0, stream>>>(Y, wt_f, f_b, Q, p1);

    // ---- 3. fused conv chain -> ctx_all slab-major (Y), mean partials ----
    //      grid = (slab, batch): a batch's 32 slab blocks dispatch adjacently
    //      so its 50KB of gates stays L2-hot across slabs and levels.
    dwconv_fused_k<<<dim3(32, BB), 448, 0, stream>>>(p1, k0, k1, k2, gates, Y, part);

    // ---- 4. global context ----
    mean_fin_k<<<BB, 128, 0, stream>>>(part, cg);
    addg3_k<<<NT * 32 / 256, 256, 0, stream>>>(Y, gates, cg);

    // ---- 5. fused h+proj -> x1 (d_out fp32); A read slab-major ----
    gemm_hproj_k<<<NT / 128, 512, 0, stream>>>(Y, wt_h, h_b, Q, wt_proj, proj_b, x, out);

    // ---- 6. LN2 -> m (Y, token-major again) ----
    ln2_k<<<NT / 4, 256, 0, stream>>>(out, ln2_g, ln2_b, Y);

    // ---- 7. fused MLP, out RMW once ----
    gemm_mlp_k<<<NT / 128, 512, 0, stream>>>(Y, wt_fc1, fc1_b, wt_fc2c, fc2_b, out);
}

// Round 7
// 929.081 us; speedup vs baseline: 1.1795x; 1.1795x over previous
//
#include <hip/hip_runtime.h>
#include <hip/hip_bf16.h>

// FocalNet block, MI355X gfx950.
// R10 (resubmit; prior run died to container-acquisition failure, no verdict):
//      abandon allocator steering (R8/R9: VGPR pinned at 64 regardless of
//      launch_bounds / waves_per_eu -> spills). Revert GEMMs to the R7
//      4-wave/64x64 shape (measured: 164 VGPR, zero spill). New lever:
//      stage each block's 32KB A-tile into padded LDS once (cooperative
//      uint4 copy), so every k-loop af read is ~12cy ds_read_b128 instead
//      of a 200-300cy global round-trip (mlp re-read A 16x, f2 8x, hproj
//      GEM1 did 8B scattered loads). Allocator-neutral: no acc pressure.

#define NT 200704   // B*H*W
#define CC 128
#define HH 56
#define WW 56
#define BB 64

typedef short short8 __attribute__((ext_vector_type(8)));
typedef float f32x4  __attribute__((ext_vector_type(4)));

__device__ __forceinline__ float b2f(unsigned short u) {
    union { float f; unsigned int i; } v; v.i = ((unsigned int)u) << 16; return v.f;
}
__device__ __forceinline__ unsigned short f2b(float f) {
    __hip_bfloat16 h = __float2bfloat16(f);
    union { __hip_bfloat16 h; unsigned short u; } v; v.h = h; return v.u;
}
// tanh-form gelu: 0.5x(1+tanh(0.79788456(x+0.044715x^3))) == x * sigmoid(2y)
__device__ __forceinline__ float gelu(float x) {
    float x2 = x * x;
    float inner = fmaf(0.044715f * x2, x, x);
    float t = exp2f(inner * -2.302118070f);   // e^{-2*0.79788456*inner}
    return x * __builtin_amdgcn_rcpf(1.0f + t);
}
__device__ __forceinline__ void cvt4(uint2 p, float* o) {
    union { float f; unsigned int i; } v;
    v.i = p.x << 16;         o[0] = v.f;
    v.i = p.x & 0xffff0000u; o[1] = v.f;
    v.i = p.y << 16;         o[2] = v.f;
    v.i = p.y & 0xffff0000u; o[3] = v.f;
}
__device__ __forceinline__ void cvt2(unsigned int p, float* o) {
    union { float f; unsigned int i; } v;
    v.i = p << 16;          o[0] = v.f;
    v.i = p & 0xffff0000u;  o[1] = v.f;
}
__device__ __forceinline__ unsigned int pack2(float a, float b) {
    return (unsigned int)f2b(a) | ((unsigned int)f2b(b) << 16);
}
__device__ __forceinline__ uint2 pack4(const float* s) {
    uint2 r;
    r.x = (unsigned int)f2b(s[0]) | ((unsigned int)f2b(s[1]) << 16);
    r.y = (unsigned int)f2b(s[2]) | ((unsigned int)f2b(s[3]) << 16);
    return r;
}
__device__ __forceinline__ short8 ldfrag_g(const unsigned short* p) {
    union { uint4 u; short8 s; } v;
    v.u = *(const uint4*)p;
    return v.s;
}
__device__ __forceinline__ short8 ldfrag_s(const unsigned short* p) {
    return *(const short8*)p;
}

// ---------------- weight prep: fp32 (K,M) row-major -> bf16 (M,K) ----------------
__global__ void transpose_bf16_k(const float* __restrict__ src, unsigned short* __restrict__ dst,
                                 int K, int M, int src_ld) {
    int idx = blockIdx.x * 256 + threadIdx.x;
    if (idx >= K * M) return;
    int k = idx / M, m = idx - k * M;
    dst[m * K + k] = f2b(src[k * src_ld + m]);
}
// fc2_w (512,128) -> (4 chunks, 128 out, 128 k-local)
__global__ void transpose_fc2c_k(const float* __restrict__ src, unsigned short* __restrict__ dst) {
    int idx = blockIdx.x * 256 + threadIdx.x;
    if (idx >= 512 * 128) return;
    int k = idx >> 7, m = idx & 127;
    int hc = k >> 7, kl = k & 127;
    dst[hc * 16384 + m * 128 + kl] = f2b(src[k * 128 + m]);
}

// ---------------- LN1 + gate dots (wave per token) ----------------
__global__ __launch_bounds__(256) void ln1_gates_k(
    const float* __restrict__ x, const float* __restrict__ g, const float* __restrict__ bta,
    const float* __restrict__ fw, const float* __restrict__ fb,
    unsigned short* __restrict__ ybf, float* __restrict__ gates)
{
    int lane = threadIdx.x & 63, wv = threadIdx.x >> 6;
    int token = blockIdx.x * 4 + wv;
    float2 xv = *(const float2*)&x[(size_t)token * CC + lane * 2];
    float s = xv.x + xv.y;
    for (int o = 32; o; o >>= 1) s += __shfl_xor(s, o);
    float mu = s * (1.0f / 128.0f);
    float d0 = xv.x - mu, d1 = xv.y - mu;
    float q2 = d0 * d0 + d1 * d1;
    for (int o = 32; o; o >>= 1) q2 += __shfl_xor(q2, o);
    float rs = rsqrtf(q2 * (1.0f / 128.0f) + 1e-5f);
    float y0 = d0 * rs * g[2 * lane] + bta[2 * lane];
    float y1 = d1 * rs * g[2 * lane + 1] + bta[2 * lane + 1];
    unsigned int pk = (unsigned int)f2b(y0) | ((unsigned int)f2b(y1) << 16);
    ((unsigned int*)ybf)[(size_t)token * 64 + lane] = pk;
    float ga[4];
    #pragma unroll
    for (int gg = 0; gg < 4; gg++)
        ga[gg] = y0 * fw[(2 * lane) * 260 + 256 + gg] + y1 * fw[(2 * lane + 1) * 260 + 256 + gg];
    for (int o = 32; o; o >>= 1) {
        #pragma unroll
        for (int gg = 0; gg < 4; gg++) ga[gg] += __shfl_xor(ga[gg], o);
    }
    if (lane == 0) {
        float4 gv = make_float4(ga[0] + fb[256], ga[1] + fb[257], ga[2] + fb[258], ga[3] + fb[259]);
        *(float4*)&gates[(size_t)token * 4] = gv;
    }
}

// ---------------- LN2 (wave per token) ----------------
__global__ __launch_bounds__(256) void ln2_k(
    const float* __restrict__ x, const float* __restrict__ g, const float* __restrict__ bta,
    unsigned short* __restrict__ ybf)
{
    int lane = threadIdx.x & 63, wv = threadIdx.x >> 6;
    int token = blockIdx.x * 4 + wv;
    float2 xv = *(const float2*)&x[(size_t)token * CC + lane * 2];
    float s = xv.x + xv.y;
    for (int o = 32; o; o >>= 1) s += __shfl_xor(s, o);
    float mu = s * (1.0f / 128.0f);
    float d0 = xv.x - mu, d1 = xv.y - mu;
    float q2 = d0 * d0 + d1 * d1;
    for (int o = 32; o; o >>= 1) q2 += __shfl_xor(q2, o);
    float rs = rsqrtf(q2 * (1.0f / 128.0f) + 1e-5f);
    float y0 = d0 * rs * g[2 * lane] + bta[2 * lane];
    float y1 = d1 * rs * g[2 * lane + 1] + bta[2 * lane + 1];
    unsigned int pk = (unsigned int)f2b(y0) | ((unsigned int)f2b(y1) << 16);
    ((unsigned int*)ybf)[(size_t)token * 64 + lane] = pk;
}

// ================= GEMM building block macros =================
// R7 shape: 128x128 tile, 4 waves 2x2, wave does 64x64 via 4x4 mfma_16x16x32.
// A-tile staged in LDS (stride 136 = 2-way-free); weights direct from global.

#define GEMM_IDS \
    const int row0 = blockIdx.x * 128; \
    const int lane = threadIdx.x & 63, wv = threadIdx.x >> 6; \
    const int wy = wv >> 1, wx = wv & 1; \
    const int q4 = lane >> 4, l16 = lane & 15; (void)row0;

#define ZERO_ACC(acc) \
    _Pragma("unroll") for (int i = 0; i < 4; i++) \
    _Pragma("unroll") for (int j = 0; j < 4; j++) acc[i][j] = (f32x4)0.0f;

#define MFMA_ALL(acc, af, bf) \
    _Pragma("unroll") for (int i = 0; i < 4; i++) \
    _Pragma("unroll") for (int j = 0; j < 4; j++) \
        acc[i][j] = __builtin_amdgcn_mfma_f32_16x16x32_bf16(af[i], bf[j], acc[i][j], 0, 0, 0);

// cooperative copy: 32KB contiguous A-tile (128 rows x 256B) -> LDS [128][136]
#define STAGE_A(As, gsrc) \
    _Pragma("unroll") for (int it = 0; it < 8; it++) { \
        int idx = it * 256 + threadIdx.x; \
        int arow = idx >> 4, c16 = idx & 15; \
        *(uint4*)&As[arow * 136 + c16 * 8] = *(const uint4*)&(gsrc)[idx * 8]; \
    }

// ---------------- fused q+ctx GEMM: t = y @ f_w[:, :256] ----------------
// q written token-major; ctx written SLAB-MAJOR [(s*NT + tok)*4 + e] via LDS stage.
__global__ __launch_bounds__(256) void gemm_f2_k(
    const unsigned short* __restrict__ A, const unsigned short* __restrict__ Wt,
    const float* __restrict__ fb,
    unsigned short* __restrict__ outq, unsigned short* __restrict__ outcT)
{
    __shared__ unsigned short As[128 * 136];
    __shared__ unsigned short Gs[32 * 268];   // [slab][tok*4+e]
    GEMM_IDS;
    STAGE_A(As, &A[(size_t)row0 * 128]);
    __syncthreads();
    for (int mo = 0; mo < 2; mo++) {
        f32x4 acc[4][4];
        ZERO_ACC(acc);
        for (int kk = 0; kk < 128; kk += 32) {
            short8 af[4], bf[4];
            #pragma unroll
            for (int i = 0; i < 4; i++)
                af[i] = ldfrag_s(&As[(wy * 64 + i * 16 + l16) * 136 + kk + q4 * 8]);
            #pragma unroll
            for (int j = 0; j < 4; j++)
                bf[j] = ldfrag_g(&Wt[(size_t)(mo * 128 + wx * 64 + j * 16 + l16) * 128 + kk + q4 * 8]);
            MFMA_ALL(acc, af, bf);
        }
        if (mo == 0) {
            #pragma unroll
            for (int i = 0; i < 4; i++)
                #pragma unroll
                for (int j = 0; j < 4; j++)
                    #pragma unroll
                    for (int rr = 0; rr < 4; rr++) {
                        int row = row0 + wy * 64 + i * 16 + q4 * 4 + rr;
                        int col = wx * 64 + j * 16 + l16;
                        outq[(size_t)row * CC + col] = f2b(acc[i][j][rr] + fb[col]);
                    }
        } else {
            #pragma unroll
            for (int i = 0; i < 4; i++)
                #pragma unroll
                for (int j = 0; j < 4; j++)
                    #pragma unroll
                    for (int rr = 0; rr < 4; rr++) {
                        int row_l = wy * 64 + i * 16 + q4 * 4 + rr;
                        int col = wx * 64 + j * 16 + l16;
                        Gs[(col >> 2) * 268 + row_l * 4 + (col & 3)] = f2b(acc[i][j][rr] + fb[128 + col]);
                    }
            __syncthreads();
            // 32 slabs x 128 tokens of uint2 -> contiguous 1KB runs per slab
            #pragma unroll
            for (int it = 0; it < 16; it++) {
                int c = it * 256 + threadIdx.x;
                int s = c >> 7, tok = c & 127;
                *(uint2*)&outcT[((size_t)s * NT + row0 + tok) * 4] =
                    *(const uint2*)&Gs[s * 268 + tok * 4];
            }
        }
    }
}

// ---------------- fused h + proj GEMM ----------------
// x_out = q * (ctx_all @ h_w + h_b);  x1 = x + x_out @ proj_w + proj_b -> d_out (fp32)
// CA (slab-major) staged into LDS [32 planes][128 tokens] of uint2.
__global__ __launch_bounds__(256) void gemm_hproj_k(
    const unsigned short* __restrict__ CA, const unsigned short* __restrict__ Wh,
    const float* __restrict__ hb, const unsigned short* __restrict__ Qm,
    const unsigned short* __restrict__ Wp, const float* __restrict__ pb,
    const float* __restrict__ xin, float* __restrict__ outp)
{
    __shared__ unsigned short As2[32 * 128 * 4];   // [s][tok] uint2, linear
    __shared__ unsigned short Gs[128 * 136];
    GEMM_IDS;
    // stage: 32 planes x 1KB (contiguous per plane)
    #pragma unroll
    for (int it = 0; it < 8; it++) {
        int idx = it * 256 + threadIdx.x;      // 2048 chunks of 16B
        int s = idx >> 6, c = idx & 63;        // c: 16B chunk within plane
        *(uint4*)&As2[(s * 128 + c * 2) * 4] =
            *(const uint4*)&CA[((size_t)s * NT + row0 + c * 2) * 4];
    }
    __syncthreads();
    f32x4 acc[4][4];
    ZERO_ACC(acc);
    for (int kk = 0; kk < 128; kk += 32) {
        short8 af[4], bf[4];
        int s0 = (kk >> 2) + q4 * 2;
        #pragma unroll
        for (int i = 0; i < 4; i++) {
            int row_l = wy * 64 + i * 16 + l16;
            union { uint2 u[2]; short8 s; } v;
            v.u[0] = *(const uint2*)&As2[(s0 * 128 + row_l) * 4];
            v.u[1] = *(const uint2*)&As2[((s0 + 1) * 128 + row_l) * 4];
            af[i] = v.s;
        }
        #pragma unroll
        for (int j = 0; j < 4; j++)
            bf[j] = ldfrag_g(&Wh[(size_t)(wx * 64 + j * 16 + l16) * 128 + kk + q4 * 8]);
        MFMA_ALL(acc, af, bf);
    }
    #pragma unroll
    for (int i = 0; i < 4; i++)
        #pragma unroll
        for (int j = 0; j < 4; j++)
            #pragma unroll
            for (int rr = 0; rr < 4; rr++) {
                int row_l = wy * 64 + i * 16 + q4 * 4 + rr;
                int col_l = wx * 64 + j * 16 + l16;
                float v = acc[i][j][rr] + hb[col_l];
                float qv = b2f(Qm[(size_t)(row0 + row_l) * CC + col_l]);
                Gs[row_l * 136 + col_l] = f2b(v * qv);
            }
    __syncthreads();
    ZERO_ACC(acc);
    for (int kk = 0; kk < 128; kk += 32) {
        short8 af[4], bf[4];
        #pragma unroll
        for (int i = 0; i < 4; i++)
            af[i] = ldfrag_s(&Gs[(wy * 64 + i * 16 + l16) * 136 + kk + q4 * 8]);
        #pragma unroll
        for (int j = 0; j < 4; j++)
            bf[j] = ldfrag_g(&Wp[(size_t)(wx * 64 + j * 16 + l16) * 128 + kk + q4 * 8]);
        MFMA_ALL(acc, af, bf);
    }
    #pragma unroll
    for (int i = 0; i < 4; i++)
        #pragma unroll
        for (int j = 0; j < 4; j++)
            #pragma unroll
            for (int rr = 0; rr < 4; rr++) {
                int row = row0 + wy * 64 + i * 16 + q4 * 4 + rr;
                int col = wx * 64 + j * 16 + l16;
                size_t oi = (size_t)row * CC + col;
                outp[oi] = acc[i][j][rr] + pb[col] + xin[oi];
            }
}

// ---------------- fused MLP: out += gelu(m@fc1+b1)@fc2 + b2 (4 hidden chunks) ----------------
__global__ __launch_bounds__(256) void gemm_mlp_k(
    const unsigned short* __restrict__ M, const unsigned short* __restrict__ W1,
    const float* __restrict__ b1, const unsigned short* __restrict__ W2,
    const float* __restrict__ b2, float* __restrict__ outp)
{
    __shared__ unsigned short As[128 * 136];
    __shared__ unsigned short Gs[128 * 136];
    GEMM_IDS;
    STAGE_A(As, &M[(size_t)row0 * 128]);
    __syncthreads();
    f32x4 accO[4][4];
    ZERO_ACC(accO);
    for (int hc = 0; hc < 4; hc++) {
        f32x4 accG[4][4];
        ZERO_ACC(accG);
        for (int kk = 0; kk < 128; kk += 32) {
            short8 af[4], bf[4];
            #pragma unroll
            for (int i = 0; i < 4; i++)
                af[i] = ldfrag_s(&As[(wy * 64 + i * 16 + l16) * 136 + kk + q4 * 8]);
            #pragma unroll
            for (int j = 0; j < 4; j++)
                bf[j] = ldfrag_g(&W1[(size_t)(hc * 128 + wx * 64 + j * 16 + l16) * 128 + kk + q4 * 8]);
            MFMA_ALL(accG, af, bf);
        }
        __syncthreads();   // prior chunk's Gs reads complete
        #pragma unroll
        for (int i = 0; i < 4; i++)
            #pragma unroll
            for (int j = 0; j < 4; j++)
                #pragma unroll
                for (int rr = 0; rr < 4; rr++) {
                    int row_l = wy * 64 + i * 16 + q4 * 4 + rr;
                    int col_l = wx * 64 + j * 16 + l16;
                    Gs[row_l * 136 + col_l] = f2b(gelu(accG[i][j][rr] + b1[hc * 128 + col_l]));
                }
        __syncthreads();
        for (int kk = 0; kk < 128; kk += 32) {
            short8 af[4], bf[4];
            #pragma unroll
            for (int i = 0; i < 4; i++)
                af[i] = ldfrag_s(&Gs[(wy * 64 + i * 16 + l16) * 136 + kk + q4 * 8]);
            #pragma unroll
            for (int j = 0; j < 4; j++)
                bf[j] = ldfrag_g(&W2[(size_t)hc * 16384 + (wx * 64 + j * 16 + l16) * 128 + kk + q4 * 8]);
            MFMA_ALL(accO, af, bf);
        }
    }
    #pragma unroll
    for (int i = 0; i < 4; i++)
        #pragma unroll
        for (int j = 0; j < 4; j++)
            #pragma unroll
            for (int rr = 0; rr < 4; rr++) {
                int row = row0 + wy * 64 + i * 16 + q4 * 4 + rr;
                int col = wx * 64 + j * 16 + l16;
                size_t oi = (size_t)row * CC + col;
                outp[oi] = accO[i][j][rr] + b2[col] + outp[oi];
            }
}

// ---------------- fused 3-level depthwise conv chain ----------------
// Block = (4-ch slab, batch image), processed as TWO independent 2-channel
// chains to keep peak live registers ~90 (no spills at the compiler's 128
// budget). uint LDS planes, row stride 65 (bank-conflict pad). Level 3 does
// not write LDS (output dead). Weights for all levels preloaded once.
template<int R, bool SUM>
__device__ __forceinline__ void conv_half(
    const unsigned int* __restrict__ bin, unsigned int* __restrict__ bout,
    const float2* __restrict__ wl2h, int t0, const float* __restrict__ gates,
    int r, int w0, int tok0, int level, float creg[7][2], float psum[2])
{
    constexpr int KS = 2 * R + 1;
    float acc7[7][2];
    #pragma unroll
    for (int i = 0; i < 7; i++) { acc7[i][0] = 0.0f; acc7[i][1] = 0.0f; }
    #pragma unroll
    for (int kh = 0; kh < KS; kh++) {
        const unsigned int* rp = &bin[(r + kh + 3 - R) * 65 + (w0 + 3 - R)];
        float xw[7 + 2 * R][2];
        #pragma unroll
        for (int j = 0; j < 7 + 2 * R; j++) cvt2(rp[j], xw[j]);
        #pragma unroll
        for (int kw = 0; kw < KS; kw++) {
            float2 w2 = wl2h[(t0 + kh * KS + kw) * 2];
            #pragma unroll
            for (int ow = 0; ow < 7; ow++) {
                acc7[ow][0] += xw[ow + kw][0] * w2.x;
                acc7[ow][1] += xw[ow + kw][1] * w2.y;
            }
        }
    }
    #pragma unroll
    for (int ow = 0; ow < 7; ow++) {
        float gt = gates[(size_t)(tok0 + ow) * 4 + level];
        float g0 = gelu(acc7[ow][0]);
        float g1 = gelu(acc7[ow][1]);
        creg[ow][0] += g0 * gt;
        creg[ow][1] += g1 * gt;
        if (SUM) { psum[0] += g0; psum[1] += g1; }
        if (!SUM) bout[(r + 3) * 65 + (w0 + 3 + ow)] = pack2(g0, g1);
    }
}

__global__ __launch_bounds__(448) void dwconv_fused_k(
    const unsigned short* __restrict__ cinT,
    const float* __restrict__ k0w, const float* __restrict__ k1w, const float* __restrict__ k2w,
    const float* __restrict__ gates,
    unsigned short* __restrict__ coutT, float* __restrict__ part)
{
    constexpr int PL = 62 * 65;
    __shared__ unsigned int bufA[2][PL];
    __shared__ unsigned int bufB[2][PL];
    __shared__ float2 wl2[83 * 2];     // [tap: 0..8 k0, 9..33 k1, 34..82 k2][half]
    __shared__ float wred[7][4];
    const int tid = threadIdx.x;
    const int slab = blockIdx.x, b = blockIdx.y;

    for (int i = tid; i < PL; i += 448) {
        bufA[0][i] = 0u; bufA[1][i] = 0u;
        bufB[0][i] = 0u; bufB[1][i] = 0u;
    }
    if (tid < 166) {
        int t = tid >> 1, h = tid & 1;
        const float* src = (t < 9) ? &k0w[t * CC]
                         : (t < 34) ? &k1w[(t - 9) * CC]
                                    : &k2w[(t - 34) * CC];
        wl2[t * 2 + h] = *(const float2*)&src[slab * 4 + h * 2];
    }
    __syncthreads();
    // slab-major: this block's plane is contiguous (3136 x 8B = 25KB)
    const unsigned short* cinS = cinT + ((size_t)slab * BB + b) * 3136 * 4;
    for (int px = tid; px < 3136; px += 448) {
        int rr = px / 56, c = px - rr * 56;
        uint2 v = *(const uint2*)&cinS[(size_t)px * 4];
        bufA[0][(rr + 3) * 65 + c + 3] = v.x;
        bufA[1][(rr + 3) * 65 + c + 3] = v.y;
    }
    __syncthreads();

    const int r = tid >> 3, wt = tid & 7, w0 = wt * 7;
    const int tok0 = b * 3136 + r * 56 + w0;
    float creg[2][7][2];
    #pragma unroll
    for (int h = 0; h < 2; h++)
        #pragma unroll
        for (int i = 0; i < 7; i++) { creg[h][i][0] = 0.0f; creg[h][i][1] = 0.0f; }
    float psum[4] = {0.0f, 0.0f, 0.0f, 0.0f};

    #pragma unroll
    for (int h = 0; h < 2; h++) {
        conv_half<1, false>(bufA[h], bufB[h], wl2 + h, 0,  gates, r, w0, tok0, 0, creg[h], &psum[h * 2]);
        __syncthreads();
        conv_half<2, false>(bufB[h], bufA[h], wl2 + h, 9,  gates, r, w0, tok0, 1, creg[h], &psum[h * 2]);
        __syncthreads();
        conv_half<3, true >(bufA[h], bufB[h], wl2 + h, 34, gates, r, w0, tok0, 2, creg[h], &psum[h * 2]);
    }

    // write ctx_all slab-major (7 consecutive uint2 per thread, coalesced per wave)
    unsigned short* coutS = coutT + ((size_t)slab * BB + b) * 3136 * 4;
    #pragma unroll
    for (int ow = 0; ow < 7; ow++) {
        float s4[4] = {creg[0][ow][0], creg[0][ow][1], creg[1][ow][0], creg[1][ow][1]};
        *(uint2*)&coutS[(size_t)(r * 56 + w0 + ow) * 4] = pack4(s4);
    }

    // block partial sums for the global mean of ctx2
    #pragma unroll
    for (int e = 0; e < 4; e++)
        for (int o = 32; o; o >>= 1) psum[e] += __shfl_xor(psum[e], o);
    if ((tid & 63) == 0) {
        #pragma unroll
        for (int e = 0; e < 4; e++) wred[tid >> 6][e] = psum[e];
    }
    __syncthreads();
    if (tid == 0) {
        float s0 = 0, s1 = 0, s2 = 0, s3 = 0;
        for (int w2 = 0; w2 < 7; w2++) {
            s0 += wred[w2][0]; s1 += wred[w2][1]; s2 += wred[w2][2]; s3 += wred[w2][3];
        }
        float4 res = make_float4(s0, s1, s2, s3);
        *(float4*)&part[((size_t)b * 32 + slab) * 4] = res;
    }
}

// ---------------- cg = gelu(mean) ----------------
__global__ void mean_fin_k(const float* __restrict__ part, float* __restrict__ cg) {
    int b = blockIdx.x, c = threadIdx.x;
    cg[b * CC + c] = gelu(part[b * CC + c] * (1.0f / 3136.0f));
}

// ---------------- acc += cg[b] * gate3 (slab-major acc) ----------------
__global__ __launch_bounds__(256) void addg3_k(
    unsigned short* acc, const float* __restrict__ gates, const float* __restrict__ cg)
{
    unsigned int idx4 = blockIdx.x * 256 + threadIdx.x;   // uint2 chunk over 32*NT
    unsigned int s   = idx4 / NT;
    unsigned int tok = idx4 - s * NT;
    unsigned int b   = tok / 3136;
    float g3 = gates[(size_t)tok * 4 + 3];
    const float* cgp = &cg[b * CC + s * 4];
    uint2 v = *(uint2*)&acc[(size_t)idx4 * 4];
    float f[4];
    cvt4(v, f);
    #pragma unroll
    for (int e = 0; e < 4; e++) f[e] += cgp[e] * g3;
    *(uint2*)&acc[(size_t)idx4 * 4] = pack4(f);
}

extern "C" void kernel_launch(void* const* d_in, const int* in_sizes, int n_in,
                              void* d_out, int out_size, void* d_ws, size_t ws_size,
                              hipStream_t stream) {
    (void)in_sizes; (void)n_in; (void)out_size; (void)ws_size;
    const float* x      = (const float*)d_in[0];
    const float* f_w    = (const float*)d_in[1];
    const float* f_b    = (const float*)d_in[2];
    const float* k0     = (const float*)d_in[3];
    const float* k1     = (const float*)d_in[4];
    const float* k2     = (const float*)d_in[5];
    const float* h_w    = (const float*)d_in[6];
    const float* h_b    = (const float*)d_in[7];
    const float* proj_w = (const float*)d_in[8];
    const float* proj_b = (const float*)d_in[9];
    const float* ln1_g  = (const float*)d_in[10];
    const float* ln1_b  = (const float*)d_in[11];
    const float* ln2_g  = (const float*)d_in[12];
    const float* ln2_b  = (const float*)d_in[13];
    const float* fc1_w  = (const float*)d_in[14];
    const float* fc1_b  = (const float*)d_in[15];
    const float* fc2_w  = (const float*)d_in[16];
    const float* fc2_b  = (const float*)d_in[17];
    float* out = (float*)d_out;

    // ---- workspace bump allocator (256B aligned), total ~103.3 MB ----
    size_t off = 0;
    auto alloc = [&](size_t bytes) -> char* {
        char* p = (char*)d_ws + off;
        off += (bytes + 255) & ~(size_t)255;
        return p;
    };
    unsigned short* wt_f    = (unsigned short*)alloc(256 * 128 * 2);
    unsigned short* wt_h    = (unsigned short*)alloc(128 * 128 * 2);
    unsigned short* wt_proj = (unsigned short*)alloc(128 * 128 * 2);
    unsigned short* wt_fc1  = (unsigned short*)alloc(512 * 128 * 2);
    unsigned short* wt_fc2c = (unsigned short*)alloc(512 * 128 * 2);
    unsigned short* Y       = (unsigned short*)alloc((size_t)NT * CC * 2); // y -> ctx_all(T) -> m
    unsigned short* Q       = (unsigned short*)alloc((size_t)NT * CC * 2); // q
    float*          gates   = (float*)alloc((size_t)NT * 4 * 4);
    float*          part    = (float*)alloc(BB * CC * 4);
    float*          cg      = (float*)alloc(BB * CC * 4);

    // ctx (slab-major) lives in d_out's upper half until the conv consumes it
    unsigned short* p1 = (unsigned short*)d_out + (size_t)NT * CC;

    // ---- 0. weight prep ----
    transpose_bf16_k<<<(128 * 256 + 255) / 256, 256, 0, stream>>>(f_w, wt_f, 128, 256, 260);
    transpose_bf16_k<<<(128 * 128 + 255) / 256, 256, 0, stream>>>(h_w, wt_h, 128, 128, 128);
    transpose_bf16_k<<<(128 * 128 + 255) / 256, 256, 0, stream>>>(proj_w, wt_proj, 128, 128, 128);
    transpose_bf16_k<<<(128 * 512 + 255) / 256, 256, 0, stream>>>(fc1_w, wt_fc1, 128, 512, 512);
    transpose_fc2c_k<<<(512 * 128 + 255) / 256, 256, 0, stream>>>(fc2_w, wt_fc2c);

    // ---- 1. LN1 + gates ----
    ln1_gates_k<<<NT / 4, 256, 0, stream>>>(x, ln1_g, ln1_b, f_w, f_b, Y, gates);

    // ---- 2. q + ctx (ctx slab-major) in one GEMM kernel ----
    gemm_f2_k<<<NT / 128, 256, 0, stream>>>(Y, wt_f, f_b, Q, p1);

    // ---- 3. fused conv chain -> ctx_all slab-major (Y), mean partials ----
    //      grid = (slab, batch): a batch's 32 slab blocks dispatch adjacently
    //      so its 50KB of gates stays L2-hot across slabs and levels.
    dwconv_fused_k<<<dim3(32, BB), 448, 0, stream>>>(p1, k0, k1, k2, gates, Y, part);

    // ---- 4. global context ----
    mean_fin_k<<<BB, 128, 0, stream>>>(part, cg);
    addg3_k<<<NT * 32 / 256, 256, 0, stream>>>(Y, gates, cg);

    // ---- 5. fused h+proj -> x1 (d_out fp32); A staged from slab-major ----
    gemm_hproj_k<<<NT / 128, 256, 0, stream>>>(Y, wt_h, h_b, Q, wt_proj, proj_b, x, out);

    // ---- 6. LN2 -> m (Y, token-major again) ----
    ln2_k<<<NT / 4, 256, 0, stream>>>(out, ln2_g, ln2_b, Y);

    // ---- 7. fused MLP, out RMW once ----
    gemm_mlp_k<<<NT / 128, 256, 0, stream>>>(Y, wt_fc1, fc1_b, wt_fc2c, fc2_b, out);
}